// Round 10
// baseline (164.972 us; speedup 1.0000x reference)
//
#include <hip/hip_runtime.h>

#define NN 16384
#define DD 512
#define HH 64
#define LL 7
#define NAGG 256           // agg blocks (= partial copies)
#define JPB  (NN / NAGG)   // 64 j's per agg block
#define CHROWS 4           // contiguous rows per work chunk
#define NCHUNK (NN / CHROWS)
#define DEGB 2048          // persistent deg blocks (8/CU, full occupancy)

typedef float f32x4 __attribute__((ext_vector_type(4)));

// ws floats layout:
// [0 .. 16384)                  qv[NN]
// [16384]                       S (float)
// [16392]                       chunk counter (int, memset to 0 each launch)
// [16400 .. 16400+NAGG*8)       cpart[NAGG][8]
// [20480 .. 20480+NAGG*7*512)   gpart[NAGG][7][512]   (~3.6 MB)
#define WS_QV  0
#define WS_S   16384
#define WS_CTR 16392
#define WS_CP  16400
#define WS_GP  20480

// Kernel 1: persistent blocks steal 4-contiguous-row chunks (DRAM page locality
// + perfect balance). Gates = one broadcast float4 from the L2-hot index row.
// All row streaming via nontemporal loads (R7/R9: any plain fraction regresses).
__global__ void k_deg(const float* __restrict__ matrix,
                      const int* __restrict__ pidx,
                      float* __restrict__ qv,
                      int* __restrict__ counter) {
    __shared__ float sdata[CHROWS][4];
    __shared__ int schunk;
    int t = threadIdx.x;
    int lane = t & 63;
    int wid = t >> 6;
    int idx = *pidx;
    const f32x4* grow = (const f32x4*)(matrix + (size_t)idx * NN);

    for (;;) {
        if (t == 0) schunk = atomicAdd(counter, 1);
        __syncthreads();
        int c = schunk;
        if (c >= NCHUNK) break;
        int jbase = c * CHROWS;
        f32x4 gate = grow[c];                     // broadcast float4, L2-hot

        float vsum[CHROWS];
        #pragma unroll
        for (int k = 0; k < CHROWS; ++k) vsum[k] = 0.f;

        #pragma unroll
        for (int k = 0; k < CHROWS; ++k) {
            if (gate[k] != 0.f) {                 // block-uniform branch
                const f32x4* r4 = (const f32x4*)(matrix + (size_t)(jbase + k) * NN);
                float v0 = 0.f, v1 = 0.f, v2 = 0.f, v3 = 0.f;
                #pragma unroll
                for (int it = 0; it < 4; ++it) {
                    f32x4 a  = __builtin_nontemporal_load(&r4[t + (it * 4 + 0) * 256]);
                    f32x4 b  = __builtin_nontemporal_load(&r4[t + (it * 4 + 1) * 256]);
                    f32x4 cc = __builtin_nontemporal_load(&r4[t + (it * 4 + 2) * 256]);
                    f32x4 d  = __builtin_nontemporal_load(&r4[t + (it * 4 + 3) * 256]);
                    v0 += a.x + a.y + a.z + a.w;
                    v1 += b.x + b.y + b.z + b.w;
                    v2 += cc.x + cc.y + cc.z + cc.w;
                    v3 += d.x + d.y + d.z + d.w;
                }
                vsum[k] = (v0 + v1) + (v2 + v3);
            }
        }

        #pragma unroll
        for (int k = 0; k < CHROWS; ++k) {
            float v = vsum[k];
            #pragma unroll
            for (int off = 32; off > 0; off >>= 1)
                v += __shfl_down(v, off);
            if (lane == 0) sdata[k][wid] = v;
        }
        __syncthreads();
        if (t < CHROWS) {
            float deg = (sdata[t][0] + sdata[t][1]) + (sdata[t][2] + sdata[t][3]);
            qv[jbase + t] = deg > 0.f ? rsqrtf(deg) : 0.f;
        }
        __syncthreads();   // protect schunk/sdata for next trip
    }
}

// Kernel 2 (R6 exact): per-block partial g'/c' over dense affine j, 8-deep ILP.
__global__ void k_agg(const float* __restrict__ matrix,
                      const float* __restrict__ xf,
                      const int* __restrict__ lab,
                      const int* __restrict__ pidx,
                      const float* __restrict__ bp,
                      const float* __restrict__ qv,
                      float* __restrict__ gpart,
                      float* __restrict__ cpart,
                      float* __restrict__ Sout,
                      float* __restrict__ out) {
    __shared__ float sS[4];
    int t = threadIdx.x;            // 256, each owns 2 feature dims
    int b = blockIdx.x;
    int d0 = t * 2;
    float2 acc[LL];
    #pragma unroll
    for (int l = 0; l < LL; ++l) acc[l] = make_float2(0.f, 0.f);
    float cacc[LL] = {0.f, 0.f, 0.f, 0.f, 0.f, 0.f, 0.f};

    #pragma unroll 1
    for (int trip = 0; trip < JPB / 8; ++trip) {      // 8 trips, 8-deep
        int jj[8];
        float qq[8];
        #pragma unroll
        for (int k = 0; k < 8; ++k) {
            jj[k] = b + (trip * 8 + k) * NAGG;
            qq[k] = qv[jj[k]];                         // uniform broadcast load
        }
        #pragma unroll
        for (int k = 0; k < 8; ++k) {
            if (qq[k] != 0.f) {                        // block-uniform branch
                float2 xv = *(const float2*)(xf + (size_t)jj[k] * DD + d0);
                float wl[LL];
                #pragma unroll
                for (int l = 0; l < LL; ++l)
                    wl[l] = qq[k] * (float)lab[jj[k] * LL + l];
                #pragma unroll
                for (int l = 0; l < LL; ++l) {
                    acc[l].x = fmaf(wl[l], xv.x, acc[l].x);
                    acc[l].y = fmaf(wl[l], xv.y, acc[l].y);
                }
                #pragma unroll
                for (int l = 0; l < LL; ++l) cacc[l] += wl[l];
            }
        }
    }
    #pragma unroll
    for (int l = 0; l < LL; ++l)
        *(float2*)(gpart + ((size_t)b * LL + l) * DD + d0) = acc[l];
    if (t == 0) {
        #pragma unroll
        for (int l = 0; l < LL; ++l) cpart[b * 8 + l] = cacc[l];
    }
    if (b == 0) {
        int idx = *pidx;
        const f32x4* r4 = (const f32x4*)(matrix + (size_t)idx * NN);
        float v = 0.f;
        #pragma unroll
        for (int it = 0; it < 16; ++it) {
            f32x4 a = r4[t + it * 256];
            v += a.x + a.y + a.z + a.w;
        }
        #pragma unroll
        for (int off = 32; off > 0; off >>= 1)
            v += __shfl_down(v, off);
        if ((t & 63) == 0) sS[t >> 6] = v;
        __syncthreads();
        if (t == 0) {
            Sout[0] = (sS[0] + sS[1]) + (sS[2] + sS[3]);
            #pragma unroll
            for (int l = 0; l < LL; ++l) out[l] = bp[l];
        }
    }
}

// Kernel 3 (R6 exact): 8 blocks, 256 threads; 4-wave-split partial reduce.
__global__ void k_final(const float* __restrict__ xf,
                        const float* __restrict__ W2,
                        const float* __restrict__ b2,
                        const float* __restrict__ Wp,
                        const int* __restrict__ pidx,
                        const float* __restrict__ gpart,
                        const float* __restrict__ cpart,
                        const float* __restrict__ Sf,
                        float* __restrict__ out) {
    __shared__ float glp[4][DD];
    __shared__ float gl[DD];
    __shared__ float csd[4];
    __shared__ float csum_s;
    __shared__ float out_acc[LL];
    int t = threadIdx.x;
    int b = blockIdx.x;
    int lane = t & 63;
    int wid = t >> 6;
    int idx = *pidx;

    if (b >= 1) {
        int l = b - 1;
        float2 s[4];
        #pragma unroll
        for (int q = 0; q < 4; ++q) s[q] = make_float2(0.f, 0.f);
        #pragma unroll 4
        for (int pbi = 0; pbi < NAGG / 4; ++pbi) {
            int pb = wid * (NAGG / 4) + pbi;
            const float* gb = gpart + ((size_t)pb * LL + l) * DD;
            #pragma unroll
            for (int q = 0; q < 4; ++q) {
                float2 v = *(const float2*)(gb + (lane + q * 64) * 2);
                s[q].x += v.x; s[q].y += v.y;
            }
        }
        #pragma unroll
        for (int q = 0; q < 4; ++q) {
            glp[wid][(lane + q * 64) * 2]     = s[q].x;
            glp[wid][(lane + q * 64) * 2 + 1] = s[q].y;
        }
        float cv = cpart[t * 8 + l];
        #pragma unroll
        for (int off = 32; off > 0; off >>= 1)
            cv += __shfl_down(cv, off);
        if (lane == 0) csd[wid] = cv;
    }
    if (t < LL) out_acc[t] = 0.f;
    __syncthreads();

    if (b >= 1) {
        gl[t * 2]     = ((glp[0][t * 2]     + glp[1][t * 2])
                       + (glp[2][t * 2]     + glp[3][t * 2]));
        gl[t * 2 + 1] = ((glp[0][t * 2 + 1] + glp[1][t * 2 + 1])
                       + (glp[2][t * 2 + 1] + glp[3][t * 2 + 1]));
        if (t == 0) csum_s = (csd[0] + csd[1]) + (csd[2] + csd[3]);
    }
    __syncthreads();

    int p = b * 64 + (t >> 2);    // concat position
    int sub = t & 3;              // d-chunk
    int h = (b == 0) ? p : (p - HH) & 63;
    int dbase = sub * 128;
    const float* src = (b == 0) ? (xf + (size_t)idx * DD) : gl;
    float s0 = 0.f, s1 = 0.f, s2 = 0.f, s3 = 0.f;
    #pragma unroll 8
    for (int d = 0; d < 128; d += 4) {
        s0 = fmaf(src[dbase + d],     W2[(dbase + d)     * HH + h], s0);
        s1 = fmaf(src[dbase + d + 1], W2[(dbase + d + 1) * HH + h], s1);
        s2 = fmaf(src[dbase + d + 2], W2[(dbase + d + 2) * HH + h], s2);
        s3 = fmaf(src[dbase + d + 3], W2[(dbase + d + 3) * HH + h], s3);
    }
    float v = (s0 + s1) + (s2 + s3);
    v += __shfl_down(v, 2);
    v += __shfl_down(v, 1);

    if (sub == 0) {
        float val;
        if (b == 0) {
            val = v + b2[p];
        } else {
            float sc = rsqrtf(Sf[0]);
            val = (v + csum_s * b2[h]) * sc;
        }
        float relu_v = val > 0.f ? val : 0.f;
        float hc = fmaxf(xf[(size_t)idx * DD + p], relu_v);
        #pragma unroll
        for (int o = 0; o < LL; ++o)
            atomicAdd(&out_acc[o], hc * Wp[p * LL + o]);
    }
    __syncthreads();
    if (t < LL) atomicAdd(&out[t], out_acc[t]);
}

extern "C" void kernel_launch(void* const* d_in, const int* in_sizes, int n_in,
                              void* d_out, int out_size, void* d_ws, size_t ws_size,
                              hipStream_t stream) {
    const float* matrix = (const float*)d_in[0];
    const float* xf     = (const float*)d_in[1];
    const float* W2     = (const float*)d_in[2];
    const float* b2     = (const float*)d_in[3];
    const float* Wp     = (const float*)d_in[4];
    const float* bp     = (const float*)d_in[5];
    const int*   lab    = (const int*)d_in[6];
    const int*   pidx   = (const int*)d_in[7];
    float* outp = (float*)d_out;
    float* wsf  = (float*)d_ws;

    hipMemsetAsync(wsf + WS_CTR, 0, sizeof(int), stream);   // chunk counter
    k_deg<<<DEGB, 256, 0, stream>>>(matrix, pidx, wsf + WS_QV,
                                    (int*)(wsf + WS_CTR));
    k_agg<<<NAGG, 256, 0, stream>>>(matrix, xf, lab, pidx, bp, wsf + WS_QV,
                                    wsf + WS_GP, wsf + WS_CP, wsf + WS_S, outp);
    k_final<<<8, 256, 0, stream>>>(xf, W2, b2, Wp, pidx,
                                   wsf + WS_GP, wsf + WS_CP, wsf + WS_S, outp);
}

// Round 11
// 134.380 us; speedup vs baseline: 1.2276x; 1.2276x over previous
//
#include <hip/hip_runtime.h>

#define NN 16384
#define DD 512
#define HH 64
#define LL 7
#define NAGG 256           // agg blocks (= partial copies)
#define JPB  (NN / NAGG)   // 64 j's per agg block
#define DEGB 4096          // deg blocks
#define RPB  (NN / DEGB)   // 4 strided rows per deg block

typedef float f32x4 __attribute__((ext_vector_type(4)));

// ws floats layout (all regions fully overwritten every replay — no init needed):
// [0 .. 16384)                  qv[NN]
// [16384]                       S (float)
// [16400 .. 16400+NAGG*8)       cpart[NAGG][8]
// [20480 .. 20480+NAGG*7*512)   gpart[NAGG][7][512]   (~3.6 MB)
#define WS_QV 0
#define WS_S  16384
#define WS_CP 16400
#define WS_GP 20480

// Kernel 1: R6 structure (4096 blocks x 4 strided rows, nt loads, backfilled
// balance) + 60 KB LDS pad -> only 2 blocks/CU resident -> 512 concurrent row
// streams instead of 2048. Tests DRAM page-locality theory for the 4.5 vs 6.3
// TB/s read gap: fewer interleaved streams per memory channel -> higher
// page-hit rate. Grid/backfill unchanged so load balance is preserved.
__global__ void k_deg(const float* __restrict__ matrix,
                      const int* __restrict__ pidx,
                      float* __restrict__ qv) {
    __shared__ float throttle[15360];   // 60 KB occupancy limiter (2 blocks/CU)
    __shared__ float sdata[RPB][4];
    int t = threadIdx.x;
    int lane = t & 63;
    int wid = t >> 6;
    int idx = *pidx;
    int j0 = blockIdx.x;

    if (__builtin_expect(idx < 0, 0)) {   // never true; keeps `throttle` allocated
        throttle[t] = (float)t;
        __syncthreads();
        qv[j0] = throttle[255];
        return;
    }

    float gate[RPB];
    #pragma unroll
    for (int k = 0; k < RPB; ++k)
        gate[k] = matrix[(size_t)idx * NN + j0 + k * DEGB];   // broadcast, L2-hot

    float vsum[RPB];
    #pragma unroll
    for (int k = 0; k < RPB; ++k) vsum[k] = 0.f;

    #pragma unroll
    for (int k = 0; k < RPB; ++k) {
        if (gate[k] != 0.f) {                       // block-uniform branch
            const f32x4* r4 = (const f32x4*)(matrix + (size_t)(j0 + k * DEGB) * NN);
            float v0 = 0.f, v1 = 0.f, v2 = 0.f, v3 = 0.f;
            #pragma unroll
            for (int it = 0; it < 4; ++it) {
                f32x4 a  = __builtin_nontemporal_load(&r4[t + (it * 4 + 0) * 256]);
                f32x4 b  = __builtin_nontemporal_load(&r4[t + (it * 4 + 1) * 256]);
                f32x4 cc = __builtin_nontemporal_load(&r4[t + (it * 4 + 2) * 256]);
                f32x4 d  = __builtin_nontemporal_load(&r4[t + (it * 4 + 3) * 256]);
                v0 += a.x + a.y + a.z + a.w;
                v1 += b.x + b.y + b.z + b.w;
                v2 += cc.x + cc.y + cc.z + cc.w;
                v3 += d.x + d.y + d.z + d.w;
            }
            vsum[k] = (v0 + v1) + (v2 + v3);
        }
    }

    #pragma unroll
    for (int k = 0; k < RPB; ++k) {
        float v = vsum[k];
        #pragma unroll
        for (int off = 32; off > 0; off >>= 1)
            v += __shfl_down(v, off);
        if (lane == 0) sdata[k][wid] = v;
    }
    __syncthreads();
    if (t < RPB) {
        float deg = (sdata[t][0] + sdata[t][1]) + (sdata[t][2] + sdata[t][3]);
        qv[j0 + t * DEGB] = deg > 0.f ? rsqrtf(deg) : 0.f;   // deg==0 <=> inactive
    }
}

// Kernel 2 (R6 exact): per-block partial g'/c' over dense affine j, 8-deep ILP.
// Stores partials (no atomics). Block 0 also computes S and seeds out = bp.
__global__ void k_agg(const float* __restrict__ matrix,
                      const float* __restrict__ xf,
                      const int* __restrict__ lab,
                      const int* __restrict__ pidx,
                      const float* __restrict__ bp,
                      const float* __restrict__ qv,
                      float* __restrict__ gpart,
                      float* __restrict__ cpart,
                      float* __restrict__ Sout,
                      float* __restrict__ out) {
    __shared__ float sS[4];
    int t = threadIdx.x;            // 256, each owns 2 feature dims
    int b = blockIdx.x;
    int d0 = t * 2;
    float2 acc[LL];
    #pragma unroll
    for (int l = 0; l < LL; ++l) acc[l] = make_float2(0.f, 0.f);
    float cacc[LL] = {0.f, 0.f, 0.f, 0.f, 0.f, 0.f, 0.f};

    #pragma unroll 1
    for (int trip = 0; trip < JPB / 8; ++trip) {      // 8 trips, 8-deep
        int jj[8];
        float qq[8];
        #pragma unroll
        for (int k = 0; k < 8; ++k) {
            jj[k] = b + (trip * 8 + k) * NAGG;
            qq[k] = qv[jj[k]];                         // uniform broadcast load
        }
        #pragma unroll
        for (int k = 0; k < 8; ++k) {
            if (qq[k] != 0.f) {                        // block-uniform branch
                float2 xv = *(const float2*)(xf + (size_t)jj[k] * DD + d0);
                float wl[LL];
                #pragma unroll
                for (int l = 0; l < LL; ++l)
                    wl[l] = qq[k] * (float)lab[jj[k] * LL + l];
                #pragma unroll
                for (int l = 0; l < LL; ++l) {
                    acc[l].x = fmaf(wl[l], xv.x, acc[l].x);
                    acc[l].y = fmaf(wl[l], xv.y, acc[l].y);
                }
                #pragma unroll
                for (int l = 0; l < LL; ++l) cacc[l] += wl[l];
            }
        }
    }
    #pragma unroll
    for (int l = 0; l < LL; ++l)
        *(float2*)(gpart + ((size_t)b * LL + l) * DD + d0) = acc[l];
    if (t == 0) {
        #pragma unroll
        for (int l = 0; l < LL; ++l) cpart[b * 8 + l] = cacc[l];
    }
    if (b == 0) {
        int idx = *pidx;
        const f32x4* r4 = (const f32x4*)(matrix + (size_t)idx * NN);
        float v = 0.f;
        #pragma unroll
        for (int it = 0; it < 16; ++it) {
            f32x4 a = r4[t + it * 256];
            v += a.x + a.y + a.z + a.w;
        }
        #pragma unroll
        for (int off = 32; off > 0; off >>= 1)
            v += __shfl_down(v, off);
        if ((t & 63) == 0) sS[t >> 6] = v;
        __syncthreads();
        if (t == 0) {
            Sout[0] = (sS[0] + sS[1]) + (sS[2] + sS[3]);
            #pragma unroll
            for (int l = 0; l < LL; ++l) out[l] = bp[l];
        }
    }
}

// Kernel 3 (R6 exact): 8 blocks, 256 threads; 4-wave-split partial reduce.
__global__ void k_final(const float* __restrict__ xf,
                        const float* __restrict__ W2,
                        const float* __restrict__ b2,
                        const float* __restrict__ Wp,
                        const int* __restrict__ pidx,
                        const float* __restrict__ gpart,
                        const float* __restrict__ cpart,
                        const float* __restrict__ Sf,
                        float* __restrict__ out) {
    __shared__ float glp[4][DD];
    __shared__ float gl[DD];
    __shared__ float csd[4];
    __shared__ float csum_s;
    __shared__ float out_acc[LL];
    int t = threadIdx.x;
    int b = blockIdx.x;
    int lane = t & 63;
    int wid = t >> 6;
    int idx = *pidx;

    if (b >= 1) {
        int l = b - 1;
        float2 s[4];
        #pragma unroll
        for (int q = 0; q < 4; ++q) s[q] = make_float2(0.f, 0.f);
        #pragma unroll 4
        for (int pbi = 0; pbi < NAGG / 4; ++pbi) {
            int pb = wid * (NAGG / 4) + pbi;
            const float* gb = gpart + ((size_t)pb * LL + l) * DD;
            #pragma unroll
            for (int q = 0; q < 4; ++q) {
                float2 v = *(const float2*)(gb + (lane + q * 64) * 2);
                s[q].x += v.x; s[q].y += v.y;
            }
        }
        #pragma unroll
        for (int q = 0; q < 4; ++q) {
            glp[wid][(lane + q * 64) * 2]     = s[q].x;
            glp[wid][(lane + q * 64) * 2 + 1] = s[q].y;
        }
        float cv = cpart[t * 8 + l];
        #pragma unroll
        for (int off = 32; off > 0; off >>= 1)
            cv += __shfl_down(cv, off);
        if (lane == 0) csd[wid] = cv;
    }
    if (t < LL) out_acc[t] = 0.f;
    __syncthreads();

    if (b >= 1) {
        gl[t * 2]     = ((glp[0][t * 2]     + glp[1][t * 2])
                       + (glp[2][t * 2]     + glp[3][t * 2]));
        gl[t * 2 + 1] = ((glp[0][t * 2 + 1] + glp[1][t * 2 + 1])
                       + (glp[2][t * 2 + 1] + glp[3][t * 2 + 1]));
        if (t == 0) csum_s = (csd[0] + csd[1]) + (csd[2] + csd[3]);
    }
    __syncthreads();

    int p = b * 64 + (t >> 2);    // concat position
    int sub = t & 3;              // d-chunk
    int h = (b == 0) ? p : (p - HH) & 63;
    int dbase = sub * 128;
    const float* src = (b == 0) ? (xf + (size_t)idx * DD) : gl;
    float s0 = 0.f, s1 = 0.f, s2 = 0.f, s3 = 0.f;
    #pragma unroll 8
    for (int d = 0; d < 128; d += 4) {
        s0 = fmaf(src[dbase + d],     W2[(dbase + d)     * HH + h], s0);
        s1 = fmaf(src[dbase + d + 1], W2[(dbase + d + 1) * HH + h], s1);
        s2 = fmaf(src[dbase + d + 2], W2[(dbase + d + 2) * HH + h], s2);
        s3 = fmaf(src[dbase + d + 3], W2[(dbase + d + 3) * HH + h], s3);
    }
    float v = (s0 + s1) + (s2 + s3);
    v += __shfl_down(v, 2);
    v += __shfl_down(v, 1);

    if (sub == 0) {
        float val;
        if (b == 0) {
            val = v + b2[p];
        } else {
            float sc = rsqrtf(Sf[0]);
            val = (v + csum_s * b2[h]) * sc;
        }
        float relu_v = val > 0.f ? val : 0.f;
        float hc = fmaxf(xf[(size_t)idx * DD + p], relu_v);
        #pragma unroll
        for (int o = 0; o < LL; ++o)
            atomicAdd(&out_acc[o], hc * Wp[p * LL + o]);
    }
    __syncthreads();
    if (t < LL) atomicAdd(&out[t], out_acc[t]);
}

extern "C" void kernel_launch(void* const* d_in, const int* in_sizes, int n_in,
                              void* d_out, int out_size, void* d_ws, size_t ws_size,
                              hipStream_t stream) {
    const float* matrix = (const float*)d_in[0];
    const float* xf     = (const float*)d_in[1];
    const float* W2     = (const float*)d_in[2];
    const float* b2     = (const float*)d_in[3];
    const float* Wp     = (const float*)d_in[4];
    const float* bp     = (const float*)d_in[5];
    const int*   lab    = (const int*)d_in[6];
    const int*   pidx   = (const int*)d_in[7];
    float* outp = (float*)d_out;
    float* wsf  = (float*)d_ws;

    k_deg<<<DEGB, 256, 0, stream>>>(matrix, pidx, wsf + WS_QV);
    k_agg<<<NAGG, 256, 0, stream>>>(matrix, xf, lab, pidx, bp, wsf + WS_QV,
                                    wsf + WS_GP, wsf + WS_CP, wsf + WS_S, outp);
    k_final<<<8, 256, 0, stream>>>(xf, W2, b2, Wp, pidx,
                                   wsf + WS_GP, wsf + WS_CP, wsf + WS_S, outp);
}